// Round 9
// baseline (342.144 us; speedup 1.0000x reference)
//
#include <hip/hip_runtime.h>

#define B 8
#define L 8
#define E 128
#define NN 1024
#define NODE 256
#define DEP 128
#define FF 384        // NODE + DEP
#define R 40
#define NEDGE (B * L * E)     // 8192
#define GP 8                  // edges per pre-block (same relation)
#define CHUNKS 256            // chunks per relation (covers n_r <= 2048; max ~260)

// ---------------------------------------------------------------------------
// init: out[b,n,:] = [ctx | 0]; zero s, c; zero cnt.
// ---------------------------------------------------------------------------
__global__ __launch_bounds__(256) void init_kernel(const float4* __restrict__ ctx4,
                                                   float4* __restrict__ out4,
                                                   float4* __restrict__ sc4,
                                                   int sc_count4,
                                                   int* __restrict__ cnt) {
    const float4 z = make_float4(0.f, 0.f, 0.f, 0.f);
    size_t i = (size_t)blockIdx.x * blockDim.x + threadIdx.x;
    size_t stride = (size_t)gridDim.x * blockDim.x;
    const size_t total_out4 = (size_t)B * NN * (FF / 4);
    for (size_t idx = i; idx < total_out4; idx += stride) {
        int f4 = (int)(idx % (FF / 4));
        size_t node = idx / (FF / 4);
        out4[idx] = (f4 < NODE / 4) ? ctx4[node * (NODE / 4) + f4] : z;
    }
    for (size_t idx = i; idx < (size_t)sc_count4; idx += stride) sc4[idx] = z;
    if (blockIdx.x == 0 && threadIdx.x < R) cnt[threadIdx.x] = 0;
}

// ---------------------------------------------------------------------------
// bucket: group all 8192 edge indices by relation.
// ---------------------------------------------------------------------------
__global__ __launch_bounds__(256) void bucket_kernel(const int* __restrict__ rels,
                                                     int* __restrict__ cnt,
                                                     int* __restrict__ bucket) {
    int i = blockIdx.x * blockDim.x + threadIdx.x;
    if (i < NEDGE) {
        int r = rels[i];
        int pos = atomicAdd(&cnt[r], 1);
        bucket[r * NEDGE + pos] = i;
    }
}

// ---------------------------------------------------------------------------
// pre v2: 1-wave blocks. Each block handles GP same-relation edges.
// Lane owns W_ctx rows (lane) and (lane+64), streamed from global into VGPRs;
// feat read as wave-uniform global float4 loads (1 L1 line each, VMEM pipe,
// no LDS broadcast). pre[gi,d] = (W_ctx[r][d,:]·ctx[b,t,:])·m
// ---------------------------------------------------------------------------
__global__ __launch_bounds__(64) void pre_kernel(const float* __restrict__ W,
                                                 const int* __restrict__ tails,
                                                 const float* __restrict__ mask,
                                                 const float* __restrict__ ctx,
                                                 const int* __restrict__ cnt,
                                                 const int* __restrict__ bucket,
                                                 float* __restrict__ pre) {
    int r = blockIdx.x / CHUNKS;
    int chunk = blockIdx.x % CHUNKS;
    int n = cnt[r];
    int start = chunk * GP;
    if (start >= n) return;
    int ng = min(GP, n - start);
    int lane = threadIdx.x;

    __shared__ int gis[GP];
    __shared__ float ms[GP];
    if (lane < ng) {
        int gi = bucket[r * NEDGE + start + lane];
        gis[lane] = gi;
        ms[lane] = mask[gi];
    }
    __syncthreads();

    // per-edge feat base pointers (g >= ng mapped to a valid dummy, result unused)
    const float4* f[GP];
#pragma unroll
    for (int g = 0; g < GP; ++g) {
        int gi = gis[(g < ng) ? g : 0];
        int b = gi >> 10;                 // gi = b*1024 + l*128 + e
        int t = tails[gi];
        f[g] = (const float4*)(ctx + ((size_t)b * NN + t) * NODE);
    }

    const float4* w0 = (const float4*)(W + ((size_t)r * DEP + lane) * FF);
    const float4* w1 = (const float4*)(W + ((size_t)r * DEP + lane + 64) * FF);

    float acc0[GP], acc1[GP];
#pragma unroll
    for (int g = 0; g < GP; ++g) { acc0[g] = 0.f; acc1[g] = 0.f; }

    for (int k = 0; k < NODE / 4; ++k) {
        float4 wa = w0[k];
        float4 wb = w1[k];
#pragma unroll
        for (int g = 0; g < GP; ++g) {
            float4 fv = f[g][k];
            acc0[g] = fmaf(wa.x, fv.x, acc0[g]);
            acc0[g] = fmaf(wa.y, fv.y, acc0[g]);
            acc0[g] = fmaf(wa.z, fv.z, acc0[g]);
            acc0[g] = fmaf(wa.w, fv.w, acc0[g]);
            acc1[g] = fmaf(wb.x, fv.x, acc1[g]);
            acc1[g] = fmaf(wb.y, fv.y, acc1[g]);
            acc1[g] = fmaf(wb.z, fv.z, acc1[g]);
            acc1[g] = fmaf(wb.w, fv.w, acc1[g]);
        }
    }
    for (int g = 0; g < ng; ++g) {
        pre[(size_t)gis[g] * DEP + lane]      = acc0[g] * ms[g];
        pre[(size_t)gis[g] * DEP + lane + 64] = acc1[g] * ms[g];
    }
}

// ---------------------------------------------------------------------------
// edge (per layer, serial): msg = pre[gi] + (W_dep[r]·child[t])·m, scatter-add.
// W_dep distinct bytes = 40*128*128*4 = 2.6 MB -> L2 resident per XCD.
// ---------------------------------------------------------------------------
__global__ __launch_bounds__(128) void edge2_kernel(const float* __restrict__ W,
                                                    const int* __restrict__ heads,
                                                    const int* __restrict__ tails,
                                                    const int* __restrict__ rels,
                                                    const float* __restrict__ mask,
                                                    const float* __restrict__ out,
                                                    const float* __restrict__ pre,
                                                    float* __restrict__ s,
                                                    float* __restrict__ c,
                                                    int layer) {
    int be = blockIdx.x;
    int b = be >> 7;
    int e = be & (E - 1);
    int gi = (b * L + layer) * E + e;
    int t = tails[gi], rr = rels[gi], h = heads[gi];
    float m = mask[gi];

    __shared__ float4 ch4[DEP / 4];   // tail child row, 512 B
    int tid = threadIdx.x;
    if (tid < DEP / 4)
        ch4[tid] = ((const float4*)(out + ((size_t)b * NN + t) * FF + NODE))[tid];
    __syncthreads();

    if (m != 0.f) {
        const float4* w4 = (const float4*)(W + ((size_t)rr * DEP + tid) * FF + NODE);
        float acc = 0.f;
#pragma unroll
        for (int k = 0; k < DEP / 4; ++k) {
            float4 w = w4[k];
            float4 fch = ch4[k];
            acc = fmaf(w.x, fch.x, acc);
            acc = fmaf(w.y, fch.y, acc);
            acc = fmaf(w.z, fch.z, acc);
            acc = fmaf(w.w, fch.w, acc);
        }
        float msg = pre[(size_t)gi * DEP + tid] + acc * m;
        atomicAdd(&s[((size_t)b * NN + h) * DEP + tid], msg);
        if (tid == 0) atomicAdd(&c[(size_t)b * NN + h], m);
    }
}

// ---------------------------------------------------------------------------
// node: 16 nodes per block with early-out. Only nodes with c>0 have nonzero s
// (so untouched s rows need no clearing). child = s/max(c,1); reset s,c.
// ---------------------------------------------------------------------------
__global__ __launch_bounds__(128) void node_kernel(float* __restrict__ out,
                                                   float* __restrict__ s,
                                                   float* __restrict__ c) {
    int nbase = blockIdx.x * 16;
    int tid = threadIdx.x;
    __shared__ float cvs[16];
    if (tid < 16) cvs[tid] = c[nbase + tid];
    __syncthreads();
#pragma unroll
    for (int k = 0; k < 16; ++k) {
        float cv = cvs[k];
        if (cv > 0.f) {
            int node = nbase + k;
            size_t si = (size_t)node * DEP + tid;
            out[(size_t)node * FF + NODE + tid] = s[si] / fmaxf(cv, 1.f);
            s[si] = 0.f;
        }
    }
    if (tid < 16 && cvs[tid] > 0.f) c[nbase + tid] = 0.f;
}

extern "C" void kernel_launch(void* const* d_in, const int* in_sizes, int n_in,
                              void* d_out, int out_size, void* d_ws, size_t ws_size,
                              hipStream_t stream) {
    const float* ctx  = (const float*)d_in[0];   // [B,N,NODE]
    const float* W    = (const float*)d_in[1];   // [R,DEP,F]
    const int* heads  = (const int*)d_in[2];     // [B,L,E]
    const int* tails  = (const int*)d_in[3];
    const int* rels   = (const int*)d_in[4];
    const float* mask = (const float*)d_in[5];

    float* out = (float*)d_out;                    // [B,N,F]

    float* s   = (float*)d_ws;                     // [B,N,DEP]
    float* c   = s + (size_t)B * NN * DEP;         // [B,N]
    float* pre = c + (size_t)B * NN;               // [B,L,E,DEP]
    int* cnt   = (int*)(pre + (size_t)NEDGE * DEP);// [R]
    int* bucket = cnt + 64;                        // [R,NEDGE]

    int sc_count4 = (B * NN * DEP + B * NN) / 4;   // zero s and c together

    init_kernel<<<2048, 256, 0, stream>>>((const float4*)ctx, (float4*)out,
                                          (float4*)d_ws, sc_count4, cnt);
    bucket_kernel<<<(NEDGE + 255) / 256, 256, 0, stream>>>(rels, cnt, bucket);
    pre_kernel<<<R * CHUNKS, 64, 0, stream>>>(W, tails, mask, ctx, cnt, bucket, pre);

    for (int l = 0; l < L; ++l) {
        edge2_kernel<<<B * E, 128, 0, stream>>>(W, heads, tails, rels, mask,
                                                out, pre, s, c, l);
        node_kernel<<<(B * NN) / 16, 128, 0, stream>>>(out, s, c);
    }
}

// Round 12
// 211.706 us; speedup vs baseline: 1.6161x; 1.6161x over previous
//
#include <hip/hip_runtime.h>

#define B 8
#define L 8
#define E 128
#define NN 1024
#define NODE 256
#define DEP 128
#define FF 384        // NODE + DEP
#define R 40
#define NEDGE (B * L * E)     // 8192
#define GP 8                  // edges per pre-block (same relation)
#define CHUNKS 256            // chunks per relation
#define K4C (NODE / 4)        // 64 float4 steps (ctx part)
#define K4D (DEP / 4)         // 32 float4 steps (dep part)

// ---------------------------------------------------------------------------
// init: out[b,n,:] = [ctx | 0]; zero s, c; zero cnt.
// ---------------------------------------------------------------------------
__global__ __launch_bounds__(256) void init_kernel(const float4* __restrict__ ctx4,
                                                   float4* __restrict__ out4,
                                                   float4* __restrict__ sc4,
                                                   int sc_count4,
                                                   int* __restrict__ cnt) {
    const float4 z = make_float4(0.f, 0.f, 0.f, 0.f);
    size_t i = (size_t)blockIdx.x * blockDim.x + threadIdx.x;
    size_t stride = (size_t)gridDim.x * blockDim.x;
    const size_t total_out4 = (size_t)B * NN * (FF / 4);
    for (size_t idx = i; idx < total_out4; idx += stride) {
        int f4 = (int)(idx % (FF / 4));
        size_t node = idx / (FF / 4);
        out4[idx] = (f4 < NODE / 4) ? ctx4[node * (NODE / 4) + f4] : z;
    }
    for (size_t idx = i; idx < (size_t)sc_count4; idx += stride) sc4[idx] = z;
    if (blockIdx.x == 0 && threadIdx.x < R) cnt[threadIdx.x] = 0;
}

// ---------------------------------------------------------------------------
// pack: k-major repack of W so lanes read coalesced at matvec time.
//   Wt[r][k4][d] = W[r][d][4*k4 .. +3]          (ctx part, k4 in [0,64))
//   Wd[r][k4][d] = W[r][d][256 + 4*k4 .. +3]    (dep part, k4 in [0,32))
// One-time, 7.9 MB, write-coalesced.
// ---------------------------------------------------------------------------
__global__ __launch_bounds__(256) void pack_kernel(const float4* __restrict__ W4,
                                                   float4* __restrict__ Wt,
                                                   float4* __restrict__ Wd) {
    int tid = blockIdx.x * 256 + threadIdx.x;
    if (tid >= R * (FF / 4) * DEP) return;          // 40*96*128
    int r = tid / ((FF / 4) * DEP);
    int rem = tid % ((FF / 4) * DEP);
    int k4 = rem / DEP;
    int d = rem % DEP;
    float4 v = W4[((size_t)r * DEP + d) * (FF / 4) + k4];
    if (k4 < K4C) Wt[((size_t)r * K4C + k4) * DEP + d] = v;
    else          Wd[((size_t)r * K4D + (k4 - K4C)) * DEP + d] = v;
}

// ---------------------------------------------------------------------------
// bucket: group all 8192 edge indices by relation.
// ---------------------------------------------------------------------------
__global__ __launch_bounds__(256) void bucket_kernel(const int* __restrict__ rels,
                                                     int* __restrict__ cnt,
                                                     int* __restrict__ bucket) {
    int i = blockIdx.x * blockDim.x + threadIdx.x;
    if (i < NEDGE) {
        int r = rels[i];
        int pos = atomicAdd(&cnt[r], 1);
        bucket[r * NEDGE + pos] = i;
    }
}

// ---------------------------------------------------------------------------
// pre v3: 1 wave per block, GP same-relation edges.
// Per k4 step: 2 coalesced float4 loads of Wt (lanes d and d+64 -> contiguous
// 2 KB), broadcast LDS reads of staged feat, 64 v_fma. VALU-bound.
// pre[gi,d] = (W_ctx[r][d,:] . ctx[b,t,:]) * m
// ---------------------------------------------------------------------------
__global__ __launch_bounds__(64) void pre_kernel(const float4* __restrict__ Wt,
                                                 const int* __restrict__ tails,
                                                 const float* __restrict__ mask,
                                                 const float4* __restrict__ ctx4,
                                                 const int* __restrict__ cnt,
                                                 const int* __restrict__ bucket,
                                                 float* __restrict__ pre) {
    int r = blockIdx.x / CHUNKS;
    int chunk = blockIdx.x % CHUNKS;
    int n = cnt[r];
    int start = chunk * GP;
    if (start >= n) return;
    int ng = min(GP, n - start);
    int lane = threadIdx.x;

    __shared__ int gis[GP];
    __shared__ float ms[GP];
    __shared__ float4 feat[GP][K4C];   // 8 KB

    if (lane < ng) {
        int gi = bucket[r * NEDGE + start + lane];
        gis[lane] = gi;
        ms[lane] = mask[gi];
    }
    __syncthreads();
    for (int g = 0; g < ng; ++g) {      // one coalesced 1 KB row load per edge
        int gi = gis[g];
        int b = gi >> 10;               // gi = b*1024 + l*128 + e
        int t = tails[gi];
        feat[g][lane] = ctx4[((size_t)b * NN + t) * K4C + lane];
    }
    __syncthreads();

    const float4* wr = Wt + (size_t)r * K4C * DEP;
    float acc0[GP], acc1[GP];
#pragma unroll
    for (int g = 0; g < GP; ++g) { acc0[g] = 0.f; acc1[g] = 0.f; }

    for (int k4 = 0; k4 < K4C; ++k4) {
        float4 w0 = wr[k4 * DEP + lane];        // coalesced
        float4 w1 = wr[k4 * DEP + lane + 64];   // coalesced (adjacent 1 KB)
#pragma unroll
        for (int g = 0; g < GP; ++g) {
            float4 f = feat[g][k4];             // broadcast, conflict-free
            acc0[g] = fmaf(w0.x, f.x, acc0[g]);
            acc0[g] = fmaf(w0.y, f.y, acc0[g]);
            acc0[g] = fmaf(w0.z, f.z, acc0[g]);
            acc0[g] = fmaf(w0.w, f.w, acc0[g]);
            acc1[g] = fmaf(w1.x, f.x, acc1[g]);
            acc1[g] = fmaf(w1.y, f.y, acc1[g]);
            acc1[g] = fmaf(w1.z, f.z, acc1[g]);
            acc1[g] = fmaf(w1.w, f.w, acc1[g]);
        }
    }
    for (int g = 0; g < ng; ++g) {
        size_t base = (size_t)gis[g] * DEP;
        pre[base + lane]      = acc0[g] * ms[g];
        pre[base + lane + 64] = acc1[g] * ms[g];
    }
}

// ---------------------------------------------------------------------------
// edge v3 (per layer, serial): msg = pre[gi] + (W_dep[r].child[t])*m, scatter.
// Wd reads coalesced (lane d contiguous); child row broadcast from LDS.
// Wd distinct bytes = 2.6 MB -> L2 resident.
// ---------------------------------------------------------------------------
__global__ __launch_bounds__(128) void edge2_kernel(const float4* __restrict__ Wd,
                                                    const int* __restrict__ heads,
                                                    const int* __restrict__ tails,
                                                    const int* __restrict__ rels,
                                                    const float* __restrict__ mask,
                                                    const float* __restrict__ out,
                                                    const float* __restrict__ pre,
                                                    float* __restrict__ s,
                                                    float* __restrict__ c,
                                                    int layer) {
    int be = blockIdx.x;
    int b = be >> 7;
    int e = be & (E - 1);
    int gi = (b * L + layer) * E + e;
    int t = tails[gi], rr = rels[gi], h = heads[gi];
    float m = mask[gi];

    __shared__ float4 ch[K4D];   // tail child row, 512 B
    int tid = threadIdx.x;
    if (tid < K4D)
        ch[tid] = ((const float4*)(out + ((size_t)b * NN + t) * FF + NODE))[tid];
    __syncthreads();

    if (m != 0.f) {
        const float4* wr = Wd + (size_t)rr * K4D * DEP;
        float accA = 0.f, accB = 0.f;   // 2 accs break the fma dep chain
#pragma unroll
        for (int k4 = 0; k4 < K4D; k4 += 2) {
            float4 w0 = wr[k4 * DEP + tid];
            float4 f0 = ch[k4];
            accA = fmaf(w0.x, f0.x, accA);
            accA = fmaf(w0.y, f0.y, accA);
            accA = fmaf(w0.z, f0.z, accA);
            accA = fmaf(w0.w, f0.w, accA);
            float4 w1 = wr[(k4 + 1) * DEP + tid];
            float4 f1 = ch[k4 + 1];
            accB = fmaf(w1.x, f1.x, accB);
            accB = fmaf(w1.y, f1.y, accB);
            accB = fmaf(w1.z, f1.z, accB);
            accB = fmaf(w1.w, f1.w, accB);
        }
        float msg = pre[(size_t)gi * DEP + tid] + (accA + accB) * m;
        atomicAdd(&s[((size_t)b * NN + h) * DEP + tid], msg);
        if (tid == 0) atomicAdd(&c[(size_t)b * NN + h], m);
    }
}

// ---------------------------------------------------------------------------
// node: 16 nodes per block with early-out. Untouched s rows stay zero, so no
// clearing needed for them. child = s/max(c,1); reset s,c.
// ---------------------------------------------------------------------------
__global__ __launch_bounds__(128) void node_kernel(float* __restrict__ out,
                                                   float* __restrict__ s,
                                                   float* __restrict__ c) {
    int nbase = blockIdx.x * 16;
    int tid = threadIdx.x;
    __shared__ float cvs[16];
    if (tid < 16) cvs[tid] = c[nbase + tid];
    __syncthreads();
#pragma unroll
    for (int k = 0; k < 16; ++k) {
        float cv = cvs[k];
        if (cv > 0.f) {
            int node = nbase + k;
            size_t si = (size_t)node * DEP + tid;
            out[(size_t)node * FF + NODE + tid] = s[si] / fmaxf(cv, 1.f);
            s[si] = 0.f;
        }
    }
    if (tid < 16 && cvs[tid] > 0.f) c[nbase + tid] = 0.f;
}

extern "C" void kernel_launch(void* const* d_in, const int* in_sizes, int n_in,
                              void* d_out, int out_size, void* d_ws, size_t ws_size,
                              hipStream_t stream) {
    const float* ctx  = (const float*)d_in[0];   // [B,N,NODE]
    const float* W    = (const float*)d_in[1];   // [R,DEP,F]
    const int* heads  = (const int*)d_in[2];     // [B,L,E]
    const int* tails  = (const int*)d_in[3];
    const int* rels   = (const int*)d_in[4];
    const float* mask = (const float*)d_in[5];

    float* out = (float*)d_out;                    // [B,N,F]

    float* s    = (float*)d_ws;                    // [B,N,DEP]
    float* c    = s + (size_t)B * NN * DEP;        // [B,N]
    float* pre  = c + (size_t)B * NN;              // [B,L,E,DEP]
    int* cnt    = (int*)(pre + (size_t)NEDGE * DEP); // [R]
    int* bucket = cnt + 64;                        // [R,NEDGE]
    float4* Wt  = (float4*)(bucket + R * NEDGE);   // [R,64,128] (16B-aligned)
    float4* Wd  = Wt + (size_t)R * K4C * DEP;      // [R,32,128]

    int sc_count4 = (B * NN * DEP + B * NN) / 4;   // zero s and c together

    init_kernel<<<2048, 256, 0, stream>>>((const float4*)ctx, (float4*)out,
                                          (float4*)d_ws, sc_count4, cnt);
    pack_kernel<<<(R * (FF / 4) * DEP + 255) / 256, 256, 0, stream>>>(
        (const float4*)W, Wt, Wd);
    bucket_kernel<<<(NEDGE + 255) / 256, 256, 0, stream>>>(rels, cnt, bucket);
    pre_kernel<<<R * CHUNKS, 64, 0, stream>>>(Wt, tails, mask,
                                              (const float4*)ctx, cnt, bucket, pre);

    for (int l = 0; l < L; ++l) {
        edge2_kernel<<<B * E, 128, 0, stream>>>(Wd, heads, tails, rels, mask,
                                                out, pre, s, c, l);
        node_kernel<<<(B * NN) / 16, 128, 0, stream>>>(out, s, c);
    }
}